// Round 2
// baseline (1075.228 us; speedup 1.0000x reference)
//
#include <hip/hip_runtime.h>
#include <hip/hip_bf16.h>

// GPT-2 attention block. Inputs/outputs fp32 (per reference); internal compute
// bf16 MFMA with fp32 accumulate. B=4, S=1024, D=1024, H=16, hd=64.
//
// Pipeline:
//   1) convert x -> bf16; convert+transpose w_attn, w_proj -> bf16 in ws
//   2) GEMM1: QKV = x @ w_attn + b_attn          (MFMA 16x16x32 bf16) -> bf16
//   3) attention: causal softmax(QK^T/8) @ V     (wave-per-query) -> bf16
//   4) GEMM2: out = A @ w_proj + b_proj          (MFMA) -> fp32

typedef __bf16 bf16x8 __attribute__((ext_vector_type(8)));
typedef float f32x4 __attribute__((ext_vector_type(4)));

#define LDT 40  // LDS leading dim pad: 40 bf16 = 80 B -> 2-way conflict only (free)

// ---------------- convert fp32 -> bf16 (elementwise) ----------------
__global__ __launch_bounds__(256) void f32_to_bf16(
    const float* __restrict__ in, __bf16* __restrict__ out, int n) {
  int i = (blockIdx.x * 256 + threadIdx.x) * 4;
  if (i + 3 < n) {
    float4 v = *(const float4*)(in + i);
    out[i + 0] = (__bf16)v.x;
    out[i + 1] = (__bf16)v.y;
    out[i + 2] = (__bf16)v.z;
    out[i + 3] = (__bf16)v.w;
  }
}

// ---------------- convert+transpose: WT[n*K+k] = (bf16)W[k*N+n] ----------------
__global__ __launch_bounds__(256) void transpose_f32_bf16(
    const float* __restrict__ W, __bf16* __restrict__ WT, int K, int N) {
  __shared__ __bf16 tile[32][33];
  int n0 = blockIdx.x * 32, k0 = blockIdx.y * 32;
  int tx = threadIdx.x, ty = threadIdx.y;  // block (32,8)
#pragma unroll
  for (int j = 0; j < 32; j += 8)
    tile[ty + j][tx] = (__bf16)W[(size_t)(k0 + ty + j) * N + n0 + tx];
  __syncthreads();
#pragma unroll
  for (int j = 0; j < 32; j += 8)
    WT[(size_t)(n0 + ty + j) * K + k0 + tx] = tile[tx][ty + j];
}

// ---------------- GEMM: C[M,N] = A[M,K] @ BT[N,K]^T + bias ----------------
// 128x128 block tile, 256 threads (4 waves, 2x2), each wave 64x64 = 4x4 MFMA tiles.
template <typename OutT>
__global__ __launch_bounds__(256) void gemm_bt_bias(
    const __bf16* __restrict__ A,    // M x K row-major (bf16)
    const __bf16* __restrict__ BT,   // N x K row-major (bf16)
    const float* __restrict__ bias,  // N (fp32)
    OutT* __restrict__ C,            // M x N row-major
    int M, int N, int K) {
  __shared__ __bf16 sA[128 * LDT];
  __shared__ __bf16 sB[128 * LDT];

  const int tid = threadIdx.x;
  const int lane = tid & 63;
  const int wave = tid >> 6;
  const int waveM = wave >> 1, waveN = wave & 1;
  const int quad = lane >> 4;   // 0..3
  const int l16 = lane & 15;    // 0..15
  const int rowBase = blockIdx.y * 128;
  const int colBase = blockIdx.x * 128;

  // staging: each thread loads 8 bf16 (16B) per pass; 2 passes per tile
  const int sRow = tid >> 2;        // 0..63
  const int sCol = (tid & 3) * 8;   // 0,8,16,24

  f32x4 acc[4][4] = {};

  for (int k0 = 0; k0 < K; k0 += 32) {
#pragma unroll
    for (int p = 0; p < 2; ++p) {
      int r = sRow + p * 64;
      *(uint4*)(&sA[r * LDT + sCol]) =
          *(const uint4*)(&A[(size_t)(rowBase + r) * K + k0 + sCol]);
      *(uint4*)(&sB[r * LDT + sCol]) =
          *(const uint4*)(&BT[(size_t)(colBase + r) * K + k0 + sCol]);
    }
    __syncthreads();

    bf16x8 af[4], bfr[4];
#pragma unroll
    for (int mt = 0; mt < 4; ++mt)
      af[mt] = *(const bf16x8*)(&sA[(waveM * 64 + mt * 16 + l16) * LDT + quad * 8]);
#pragma unroll
    for (int nt = 0; nt < 4; ++nt)
      bfr[nt] = *(const bf16x8*)(&sB[(waveN * 64 + nt * 16 + l16) * LDT + quad * 8]);
#pragma unroll
    for (int mt = 0; mt < 4; ++mt)
#pragma unroll
      for (int nt = 0; nt < 4; ++nt)
        acc[mt][nt] = __builtin_amdgcn_mfma_f32_16x16x32_bf16(
            af[mt], bfr[nt], acc[mt][nt], 0, 0, 0);
    __syncthreads();
  }

  // epilogue: D[row=quad*4+r][col=l16] per 16x16 tile (verified m89/m91 layout)
#pragma unroll
  for (int mt = 0; mt < 4; ++mt) {
    int row = rowBase + waveM * 64 + mt * 16 + quad * 4;
#pragma unroll
    for (int nt = 0; nt < 4; ++nt) {
      int col = colBase + waveN * 64 + nt * 16 + l16;
      float bv = bias[col];
#pragma unroll
      for (int r = 0; r < 4; ++r)
        C[(size_t)(row + r) * N + col] = (OutT)(acc[mt][nt][r] + bv);
    }
  }
}

// ---------------- attention: wave-per-query causal softmax attention ----------------
// qkv layout: [B*S][3072] bf16, Q at col h*64, K at 1024+h*64, V at 2048+h*64
__global__ __launch_bounds__(256) void attn_kernel(
    const __bf16* __restrict__ qkv, __bf16* __restrict__ Aout) {
  __shared__ float P[4][1024];
  const int lane = threadIdx.x & 63;
  const int wave = threadIdx.x >> 6;
  const int qid = blockIdx.x * 4 + wave;  // (b*16 + h)*1024 + qi
  const int b = qid >> 14;
  const int h = (qid >> 10) & 15;
  const int qi = qid & 1023;

  const size_t rowStride = 3072;
  const __bf16* qptr = qkv + ((size_t)b * 1024 + qi) * rowStride + h * 64;

  float qreg[64];
#pragma unroll
  for (int d8 = 0; d8 < 8; ++d8) {
    bf16x8 v = *(const bf16x8*)(qptr + d8 * 8);
#pragma unroll
    for (int e = 0; e < 8; ++e) qreg[d8 * 8 + e] = (float)v[e];
  }

  // phase 1: scores. lane handles keys j = lane + t*64
  const __bf16* kbase = qkv + (size_t)b * 1024 * rowStride + 1024 + h * 64;
  float sc[16];
#pragma unroll
  for (int t = 0; t < 16; ++t) {
    int j = lane + t * 64;
    float s = -10000.0f;  // reference: masked = w*0 - 10000
    if (j <= qi) {
      const __bf16* krow = kbase + (size_t)j * rowStride;
      float acc = 0.f;
#pragma unroll
      for (int d8 = 0; d8 < 8; ++d8) {
        bf16x8 kv = *(const bf16x8*)(krow + d8 * 8);
#pragma unroll
        for (int e = 0; e < 8; ++e) acc += (float)kv[e] * qreg[d8 * 8 + e];
      }
      s = acc * 0.125f;  // 1/sqrt(64)
    }
    sc[t] = s;
  }

  // softmax across 1024 scores (16 per lane x 64 lanes)
  float m = sc[0];
#pragma unroll
  for (int t = 1; t < 16; ++t) m = fmaxf(m, sc[t]);
#pragma unroll
  for (int off = 32; off >= 1; off >>= 1) m = fmaxf(m, __shfl_xor(m, off));
  float sum = 0.f;
#pragma unroll
  for (int t = 0; t < 16; ++t) {
    float p = __expf(sc[t] - m);
    sc[t] = p;
    sum += p;
  }
#pragma unroll
  for (int off = 32; off >= 1; off >>= 1) sum += __shfl_xor(sum, off);

#pragma unroll
  for (int t = 0; t < 16; ++t) P[wave][lane + t * 64] = sc[t];
  __syncthreads();

  // phase 2: O[d] = sum_j P[j] * V[j][d], lane = d (coalesced V reads)
  const float inv = 1.0f / sum;
  const __bf16* vbase =
      qkv + (size_t)b * 1024 * rowStride + 2048 + h * 64 + lane;
  float o0 = 0.f, o1 = 0.f, o2 = 0.f, o3 = 0.f;
  int j = 0;
  const int jmax = qi;  // inclusive
  for (; j + 3 <= jmax; j += 4) {
    float4 p = *(const float4*)(&P[wave][j]);
    o0 += p.x * (float)vbase[(size_t)(j + 0) * rowStride];
    o1 += p.y * (float)vbase[(size_t)(j + 1) * rowStride];
    o2 += p.z * (float)vbase[(size_t)(j + 2) * rowStride];
    o3 += p.w * (float)vbase[(size_t)(j + 3) * rowStride];
  }
  for (; j <= jmax; ++j) o0 += P[wave][j] * (float)vbase[(size_t)j * rowStride];

  float o = (o0 + o1 + o2 + o3) * inv;
  Aout[((size_t)b * 1024 + qi) * 1024 + h * 64 + lane] = (__bf16)o;
}

// ---------------- launch ----------------
extern "C" void kernel_launch(void* const* d_in, const int* in_sizes, int n_in,
                              void* d_out, int out_size, void* d_ws,
                              size_t ws_size, hipStream_t stream) {
  const float* x      = (const float*)d_in[0];  // [4096,1024]
  const float* w_attn = (const float*)d_in[1];  // [1024,3072]
  const float* b_attn = (const float*)d_in[2];  // [3072]
  const float* w_proj = (const float*)d_in[3];  // [1024,1024]
  const float* b_proj = (const float*)d_in[4];  // [1024]
  float* out = (float*)d_out;                   // [4096,1024] fp32

  char* ws = (char*)d_ws;
  __bf16* WT_attn = (__bf16*)(ws);                  //  6 MB: [3072,1024] bf16
  __bf16* WT_proj = (__bf16*)(ws + 6291456);        //  2 MB: [1024,1024] bf16
  __bf16* Xb      = (__bf16*)(ws + 8388608);        //  8 MB: [4096,1024] bf16
  __bf16* QKV     = (__bf16*)(ws + 16777216);       // 24 MB: [4096,3072] bf16
  __bf16* Aattn   = (__bf16*)(ws + 41943040);       //  8 MB: [4096,1024] bf16
                                                    // total 48 MB

  transpose_f32_bf16<<<dim3(3072 / 32, 1024 / 32), dim3(32, 8), 0, stream>>>(
      w_attn, WT_attn, 1024, 3072);
  transpose_f32_bf16<<<dim3(1024 / 32, 1024 / 32), dim3(32, 8), 0, stream>>>(
      w_proj, WT_proj, 1024, 1024);
  f32_to_bf16<<<4096, 256, 0, stream>>>(x, Xb, 4096 * 1024);
  gemm_bt_bias<__bf16><<<dim3(3072 / 128, 4096 / 128), 256, 0, stream>>>(
      Xb, WT_attn, b_attn, QKV, 4096, 3072, 1024);
  attn_kernel<<<16384, 256, 0, stream>>>(QKV, Aattn);
  gemm_bt_bias<float><<<dim3(1024 / 128, 4096 / 128), 256, 0, stream>>>(
      Aattn, WT_proj, b_proj, out, 4096, 1024, 1024);
}

// Round 3
// 218.629 us; speedup vs baseline: 4.9180x; 4.9180x over previous
//
#include <hip/hip_runtime.h>
#include <hip/hip_bf16.h>

// GPT-2 attention block. Inputs/outputs fp32; internal bf16 MFMA, fp32 accum.
// B=4, S=1024, D=1024, H=16, hd=64.

typedef __bf16 bf16x8 __attribute__((ext_vector_type(8)));
typedef float f32x4 __attribute__((ext_vector_type(4)));

#define LDT 40  // GEMM LDS pad: 40 bf16 = 80 B -> 2-way conflict only (free)

// ---------------- convert fp32 -> bf16 ----------------
__global__ __launch_bounds__(256) void f32_to_bf16(
    const float* __restrict__ in, __bf16* __restrict__ out, int n) {
  int i = (blockIdx.x * 256 + threadIdx.x) * 4;
  if (i + 3 < n) {
    float4 v = *(const float4*)(in + i);
    out[i + 0] = (__bf16)v.x;
    out[i + 1] = (__bf16)v.y;
    out[i + 2] = (__bf16)v.z;
    out[i + 3] = (__bf16)v.w;
  }
}

// ---------------- convert+transpose: WT[n*K+k] = (bf16)W[k*N+n] ----------------
__global__ __launch_bounds__(256) void transpose_f32_bf16(
    const float* __restrict__ W, __bf16* __restrict__ WT, int K, int N) {
  __shared__ __bf16 tile[32][33];
  int n0 = blockIdx.x * 32, k0 = blockIdx.y * 32;
  int tx = threadIdx.x, ty = threadIdx.y;  // block (32,8)
#pragma unroll
  for (int j = 0; j < 32; j += 8)
    tile[ty + j][tx] = (__bf16)W[(size_t)(k0 + ty + j) * N + n0 + tx];
  __syncthreads();
#pragma unroll
  for (int j = 0; j < 32; j += 8)
    WT[(size_t)(n0 + ty + j) * K + k0 + tx] = tile[tx][ty + j];
}

// ---------------- GEMM: C[M,N] = A[M,K] @ BT[N,K]^T + bias ----------------
template <typename OutT>
__global__ __launch_bounds__(256) void gemm_bt_bias(
    const __bf16* __restrict__ A, const __bf16* __restrict__ BT,
    const float* __restrict__ bias, OutT* __restrict__ C, int M, int N, int K) {
  __shared__ __bf16 sA[128 * LDT];
  __shared__ __bf16 sB[128 * LDT];

  const int tid = threadIdx.x;
  const int lane = tid & 63;
  const int wave = tid >> 6;
  const int waveM = wave >> 1, waveN = wave & 1;
  const int quad = lane >> 4;
  const int l16 = lane & 15;
  const int rowBase = blockIdx.y * 128;
  const int colBase = blockIdx.x * 128;
  const int sRow = tid >> 2;
  const int sCol = (tid & 3) * 8;

  f32x4 acc[4][4] = {};

  for (int k0 = 0; k0 < K; k0 += 32) {
#pragma unroll
    for (int p = 0; p < 2; ++p) {
      int r = sRow + p * 64;
      *(uint4*)(&sA[r * LDT + sCol]) =
          *(const uint4*)(&A[(size_t)(rowBase + r) * K + k0 + sCol]);
      *(uint4*)(&sB[r * LDT + sCol]) =
          *(const uint4*)(&BT[(size_t)(colBase + r) * K + k0 + sCol]);
    }
    __syncthreads();

    bf16x8 af[4], bfr[4];
#pragma unroll
    for (int mt = 0; mt < 4; ++mt)
      af[mt] = *(const bf16x8*)(&sA[(waveM * 64 + mt * 16 + l16) * LDT + quad * 8]);
#pragma unroll
    for (int nt = 0; nt < 4; ++nt)
      bfr[nt] = *(const bf16x8*)(&sB[(waveN * 64 + nt * 16 + l16) * LDT + quad * 8]);
#pragma unroll
    for (int mt = 0; mt < 4; ++mt)
#pragma unroll
      for (int nt = 0; nt < 4; ++nt)
        acc[mt][nt] = __builtin_amdgcn_mfma_f32_16x16x32_bf16(
            af[mt], bfr[nt], acc[mt][nt], 0, 0, 0);
    __syncthreads();
  }

#pragma unroll
  for (int mt = 0; mt < 4; ++mt) {
    int row = rowBase + waveM * 64 + mt * 16 + quad * 4;
#pragma unroll
    for (int nt = 0; nt < 4; ++nt) {
      int col = colBase + waveN * 64 + nt * 16 + l16;
      float bv = bias[col];
#pragma unroll
      for (int r = 0; r < 4; ++r)
        C[(size_t)(row + r) * N + col] = (OutT)(acc[mt][nt][r] + bv);
    }
  }
}

// ---------------- flash attention, MFMA ----------------
// Block = (b, h, 64-query tile); 4 waves x 16 query rows each.
// Per 64-key tile: sK[key][d] and sVT[d][key] staged in LDS with XOR-swizzled
// 8-elem blocks (b128 frag reads at the 8-cycle wave floor); QK^T -> online
// softmax -> P via per-wave LDS round-trip (C-layout -> A-layout) -> PV.
__global__ __launch_bounds__(256) void attn_mfma(
    const __bf16* __restrict__ qkv, __bf16* __restrict__ Aout) {
  __shared__ __bf16 sK[64 * 64];
  __shared__ __bf16 sVT[64 * 64];
  __shared__ __bf16 sP[4 * 16 * 64];

  const int tid = threadIdx.x;
  const int lane = tid & 63;
  const int wave = tid >> 6;
  const int quad = lane >> 4;
  const int l16 = lane & 15;

  const int bh = blockIdx.x >> 4;          // (b*16 + h)
  const int qt = 15 - (blockIdx.x & 15);   // longest blocks first
  const int b = bh >> 4, h = bh & 15;
  const int qb = qt * 64;

  const size_t rowS = 3072;
  const __bf16* Qb = qkv + (size_t)b * 1024 * rowS + h * 64;
  const __bf16* Kb = Qb + 1024;
  const __bf16* Vb = Qb + 2048;

  // Q A-fragments (row = l16 within wave's 16 rows, k = quad*8..+7 and +32)
  bf16x8 qA0, qA1;
  {
    const __bf16* qr = Qb + (size_t)(qb + wave * 16 + l16) * rowS + quad * 8;
    qA0 = *(const bf16x8*)qr;
    qA1 = *(const bf16x8*)(qr + 32);
  }

  f32x4 Oacc[4] = {};          // [d-subtile][reg]: row q=quad*4+r, col d=n*16+l16
  float m_run[4], l_run[4];
#pragma unroll
  for (int r = 0; r < 4; ++r) { m_run[r] = -3.0e38f; l_run[r] = 0.f; }

  for (int kb = 0; kb <= qb; kb += 64) {
    __syncthreads();  // previous iter's LDS reads complete

    // ---- stage K tile: sK[key][d], d-blocks XOR-swizzled by (key&7)
    {
      const int r = tid >> 2, cq = tid & 3;
      const __bf16* gk = Kb + (size_t)(kb + r) * rowS + cq * 16;
      const int db = cq * 2;
      *(bf16x8*)(&sK[r * 64 + (((db + 0) ^ (r & 7)) << 3)]) = *(const bf16x8*)(gk);
      *(bf16x8*)(&sK[r * 64 + (((db + 1) ^ (r & 7)) << 3)]) = *(const bf16x8*)(gk + 8);
    }
    // ---- stage V^T tile: sVT[d][key], key-blocks XOR-swizzled by (d&7)
    {
      const int r = tid & 63, cb = tid >> 6;
      const __bf16* gv = Vb + (size_t)(kb + r) * rowS + cb * 16;
      bf16x8 v0 = *(const bf16x8*)(gv);
      bf16x8 v1 = *(const bf16x8*)(gv + 8);
      const int rb = r >> 3, rlo = r & 7;
#pragma unroll
      for (int i = 0; i < 8; ++i) {
        const int d0 = cb * 16 + i, d1 = d0 + 8;
        sVT[d0 * 64 + ((rb ^ (d0 & 7)) << 3) + rlo] = v0[i];
        sVT[d1 * 64 + ((rb ^ (d1 & 7)) << 3) + rlo] = v1[i];
      }
    }
    __syncthreads();

    const bool diag = (kb == qb);
    const int nmax = diag ? (wave + 1) : 4;  // key-subtiles below/at diagonal

    // ---- QK^T + scale + causal mask
    float sc[4][4];
#pragma unroll
    for (int n = 0; n < 4; ++n) {
      if (n < nmax) {
        const int key = n * 16 + l16;
        const int sw = key & 7;
        bf16x8 kB0 = *(const bf16x8*)(&sK[key * 64 + ((quad ^ sw) << 3)]);
        bf16x8 kB1 = *(const bf16x8*)(&sK[key * 64 + (((quad + 4) ^ sw) << 3)]);
        f32x4 c = {};
        c = __builtin_amdgcn_mfma_f32_16x16x32_bf16(qA0, kB0, c, 0, 0, 0);
        c = __builtin_amdgcn_mfma_f32_16x16x32_bf16(qA1, kB1, c, 0, 0, 0);
#pragma unroll
        for (int r = 0; r < 4; ++r) {
          float s = c[r] * 0.125f;
          if (diag && n == nmax - 1 && l16 > quad * 4 + r) s = -10000.f;
          sc[n][r] = s;
        }
      } else {
#pragma unroll
        for (int r = 0; r < 4; ++r) sc[n][r] = -10000.f;
      }
    }

    // ---- online softmax (per query row; 16 lanes of a quad hold one row)
    float alpha[4];
#pragma unroll
    for (int r = 0; r < 4; ++r) {
      float tmax = fmaxf(fmaxf(sc[0][r], sc[1][r]), fmaxf(sc[2][r], sc[3][r]));
      tmax = fmaxf(tmax, __shfl_xor(tmax, 1));
      tmax = fmaxf(tmax, __shfl_xor(tmax, 2));
      tmax = fmaxf(tmax, __shfl_xor(tmax, 4));
      tmax = fmaxf(tmax, __shfl_xor(tmax, 8));
      const float newm = fmaxf(m_run[r], tmax);
      alpha[r] = __expf(m_run[r] - newm);
      m_run[r] = newm;
      float ps = 0.f;
#pragma unroll
      for (int n = 0; n < 4; ++n) {
        float p = __expf(sc[n][r] - newm);
        sc[n][r] = p;
        ps += p;
      }
      ps += __shfl_xor(ps, 1);
      ps += __shfl_xor(ps, 2);
      ps += __shfl_xor(ps, 4);
      ps += __shfl_xor(ps, 8);
      l_run[r] = l_run[r] * alpha[r] + ps;
    }

    // ---- P: C-layout regs -> per-wave LDS (bf16, swizzled) -> A-fragments
    __bf16* pw = sP + wave * 1024;
    {
      const int kb8 = (l16 >> 3);
#pragma unroll
      for (int n = 0; n < 4; ++n) {
        const int blk = n * 2 + kb8;
#pragma unroll
        for (int r = 0; r < 4; ++r) {
          const int q = quad * 4 + r;
          pw[q * 64 + ((blk ^ (q & 7)) << 3) + (l16 & 7)] = (__bf16)sc[n][r];
        }
      }
    }

    // ---- rescale O, then PV
#pragma unroll
    for (int n = 0; n < 4; ++n)
#pragma unroll
      for (int r = 0; r < 4; ++r) Oacc[n][r] *= alpha[r];

    const int swq = l16 & 7;
    bf16x8 pA0 = *(const bf16x8*)(&pw[l16 * 64 + ((quad ^ swq) << 3)]);
    bf16x8 pA1 = *(const bf16x8*)(&pw[l16 * 64 + (((quad + 4) ^ swq) << 3)]);
    const bool full = !diag || wave >= 2;  // waves 0,1 at diag: keys>=32 all masked
#pragma unroll
    for (int n = 0; n < 4; ++n) {
      const int d = n * 16 + l16;
      bf16x8 vB0 = *(const bf16x8*)(&sVT[d * 64 + ((quad ^ swq) << 3)]);
      Oacc[n] = __builtin_amdgcn_mfma_f32_16x16x32_bf16(pA0, vB0, Oacc[n], 0, 0, 0);
      if (full) {
        bf16x8 vB1 = *(const bf16x8*)(&sVT[d * 64 + (((quad + 4) ^ swq) << 3)]);
        Oacc[n] = __builtin_amdgcn_mfma_f32_16x16x32_bf16(pA1, vB1, Oacc[n], 0, 0, 0);
      }
    }
  }

  // ---- epilogue: O /= l, store bf16
  float inv[4];
#pragma unroll
  for (int r = 0; r < 4; ++r) inv[r] = 1.0f / l_run[r];
#pragma unroll
  for (int n = 0; n < 4; ++n) {
#pragma unroll
    for (int r = 0; r < 4; ++r) {
      const int q = qb + wave * 16 + quad * 4 + r;
      Aout[((size_t)b * 1024 + q) * 1024 + h * 64 + n * 16 + l16] =
          (__bf16)(Oacc[n][r] * inv[r]);
    }
  }
}

// ---------------- launch ----------------
extern "C" void kernel_launch(void* const* d_in, const int* in_sizes, int n_in,
                              void* d_out, int out_size, void* d_ws,
                              size_t ws_size, hipStream_t stream) {
  const float* x      = (const float*)d_in[0];
  const float* w_attn = (const float*)d_in[1];
  const float* b_attn = (const float*)d_in[2];
  const float* w_proj = (const float*)d_in[3];
  const float* b_proj = (const float*)d_in[4];
  float* out = (float*)d_out;

  char* ws = (char*)d_ws;
  __bf16* WT_attn = (__bf16*)(ws);
  __bf16* WT_proj = (__bf16*)(ws + 6291456);
  __bf16* Xb      = (__bf16*)(ws + 8388608);
  __bf16* QKV     = (__bf16*)(ws + 16777216);
  __bf16* Aattn   = (__bf16*)(ws + 41943040);

  transpose_f32_bf16<<<dim3(3072 / 32, 1024 / 32), dim3(32, 8), 0, stream>>>(
      w_attn, WT_attn, 1024, 3072);
  transpose_f32_bf16<<<dim3(1024 / 32, 1024 / 32), dim3(32, 8), 0, stream>>>(
      w_proj, WT_proj, 1024, 1024);
  f32_to_bf16<<<4096, 256, 0, stream>>>(x, Xb, 4096 * 1024);
  gemm_bt_bias<__bf16><<<dim3(3072 / 128, 4096 / 128), 256, 0, stream>>>(
      Xb, WT_attn, b_attn, QKV, 4096, 3072, 1024);
  attn_mfma<<<1024, 256, 0, stream>>>(QKV, Aattn);
  gemm_bt_bias<float><<<dim3(1024 / 128, 4096 / 128), 256, 0, stream>>>(
      Aattn, WT_proj, b_proj, out, 4096, 1024, 1024);
}

// Round 4
// 213.744 us; speedup vs baseline: 5.0304x; 1.0229x over previous
//
#include <hip/hip_runtime.h>
#include <hip/hip_bf16.h>

// GPT-2 attention block. Inputs/outputs fp32; internal bf16 MFMA, fp32 accum.
// B=4, S=1024, D=1024, H=16, hd=64.
//
// R4: GEMMs use global_load_lds (m97 ladder step, XOR-swizzled 16B slots);
//     attention uses K-tile=128 with DMA staging (K direct, V via a global
//     pre-transpose), P aliases sK in LDS.

typedef __bf16 bf16x8 __attribute__((ext_vector_type(8)));
typedef float f32x4 __attribute__((ext_vector_type(4)));

__device__ __forceinline__ void load_lds16(const void* g, void* l) {
  __builtin_amdgcn_global_load_lds(
      (const __attribute__((address_space(1))) void*)g,
      (__attribute__((address_space(3))) void*)l, 16, 0, 0);
}

// ---------------- convert fp32 -> bf16 ----------------
__global__ __launch_bounds__(256) void f32_to_bf16(
    const float* __restrict__ in, __bf16* __restrict__ out, int n) {
  int i = (blockIdx.x * 256 + threadIdx.x) * 4;
  if (i + 3 < n) {
    float4 v = *(const float4*)(in + i);
    out[i + 0] = (__bf16)v.x;
    out[i + 1] = (__bf16)v.y;
    out[i + 2] = (__bf16)v.z;
    out[i + 3] = (__bf16)v.w;
  }
}

// ---------------- convert+transpose: WT[n*K+k] = (bf16)W[k*N+n] ----------------
__global__ __launch_bounds__(256) void transpose_f32_bf16(
    const float* __restrict__ W, __bf16* __restrict__ WT, int K, int N) {
  __shared__ __bf16 tile[32][33];
  int n0 = blockIdx.x * 32, k0 = blockIdx.y * 32;
  int tx = threadIdx.x, ty = threadIdx.y;  // block (32,8)
#pragma unroll
  for (int j = 0; j < 32; j += 8)
    tile[ty + j][tx] = (__bf16)W[(size_t)(k0 + ty + j) * N + n0 + tx];
  __syncthreads();
#pragma unroll
  for (int j = 0; j < 32; j += 8)
    WT[(size_t)(n0 + ty + j) * K + k0 + tx] = tile[tx][ty + j];
}

// ---------------- V transpose: VT[bh][d][s] from QKV ----------------
// Per store instruction all 64 lanes hit consecutive s -> 128B coalesced.
__global__ __launch_bounds__(256) void transpose_v(
    const __bf16* __restrict__ qkv, __bf16* __restrict__ VT) {
  const int lane = threadIdx.x & 63, wave = threadIdx.x >> 6;
  const int bh = blockIdx.x >> 4;
  const int kb = (blockIdx.x & 15) * 64;
  const int b = bh >> 4, h = bh & 15;
  const __bf16* src =
      qkv + ((size_t)b * 1024 + kb + lane) * 3072 + 2048 + h * 64 + wave * 16;
  bf16x8 v0 = *(const bf16x8*)src;
  bf16x8 v1 = *(const bf16x8*)(src + 8);
  __bf16* dst = VT + ((size_t)bh * 64 + wave * 16) * 1024 + kb + lane;
#pragma unroll
  for (int i = 0; i < 8; ++i) {
    dst[(size_t)i * 1024] = v0[i];
    dst[(size_t)(i + 8) * 1024] = v1[i];
  }
}

// ---------------- GEMM (m97 structure): C = A @ BT^T + bias ----------------
// 128x128 tile, BK=32, unpadded LDS [128][32], 16B slots swizzled
// slot = s ^ (r&3) ^ ((r>>2)&3)  -> fragment b128 reads are 2-way (free).
template <typename OutT>
__global__ __launch_bounds__(256) void gemm_bt_bias(
    const __bf16* __restrict__ A, const __bf16* __restrict__ BT,
    const float* __restrict__ bias, OutT* __restrict__ C, int M, int N, int K) {
  __shared__ __bf16 sA[128 * 32];
  __shared__ __bf16 sB[128 * 32];

  const int tid = threadIdx.x;
  const int lane = tid & 63;
  const int wave = tid >> 6;
  const int waveM = wave >> 1, waveN = wave & 1;
  const int quad = lane >> 4;
  const int l16 = lane & 15;
  const int rowBase = blockIdx.y * 128;
  const int colBase = blockIdx.x * 128;

  const int rIn = lane >> 2;  // 0..15 row within a 1KB issue
  const int sIn = lane & 3;   // 16B slot within row
  const int gc = sIn ^ (rIn & 3) ^ ((rIn >> 2) & 3);  // swizzled global chunk
  const int readSlot = quad ^ (l16 & 3) ^ ((l16 >> 2) & 3);

  f32x4 acc[4][4] = {};

  for (int k0 = 0; k0 < K; k0 += 32) {
    __syncthreads();  // prior iter's fragment reads done
#pragma unroll
    for (int j = 0; j < 2; ++j) {
      const int rb = wave * 32 + j * 16;  // wave-uniform
      load_lds16(&A[(size_t)(rowBase + rb + rIn) * K + k0 + gc * 8], &sA[rb * 32]);
      load_lds16(&BT[(size_t)(colBase + rb + rIn) * K + k0 + gc * 8], &sB[rb * 32]);
    }
    __syncthreads();  // staged (vmcnt drained by barrier)

    bf16x8 af[4], bfr[4];
#pragma unroll
    for (int mt = 0; mt < 4; ++mt)
      af[mt] = *(const bf16x8*)(&sA[(waveM * 64 + mt * 16 + l16) * 32 + readSlot * 8]);
#pragma unroll
    for (int nt = 0; nt < 4; ++nt)
      bfr[nt] = *(const bf16x8*)(&sB[(waveN * 64 + nt * 16 + l16) * 32 + readSlot * 8]);
#pragma unroll
    for (int mt = 0; mt < 4; ++mt)
#pragma unroll
      for (int nt = 0; nt < 4; ++nt)
        acc[mt][nt] = __builtin_amdgcn_mfma_f32_16x16x32_bf16(
            af[mt], bfr[nt], acc[mt][nt], 0, 0, 0);
  }

#pragma unroll
  for (int mt = 0; mt < 4; ++mt) {
    int row = rowBase + waveM * 64 + mt * 16 + quad * 4;
#pragma unroll
    for (int nt = 0; nt < 4; ++nt) {
      int col = colBase + waveN * 64 + nt * 16 + l16;
      float bv = bias[col];
#pragma unroll
      for (int r = 0; r < 4; ++r)
        C[(size_t)(row + r) * N + col] = (OutT)(acc[mt][nt][r] + bv);
    }
  }
}

// ---------------- flash attention, MFMA, K-tile=128, DMA staging ----------------
// Block = (b,h,64-q tile), 4 waves x 16 q rows. LDS: sK[128][64] (aliased by P
// after QK^T barrier), sV[64][128]. All tiles processed as full 128 keys with
// -10000 masking (branch-free, register-resident sc[8][4]).
__global__ __launch_bounds__(256) void attn_mfma(
    const __bf16* __restrict__ qkv, const __bf16* __restrict__ VT,
    __bf16* __restrict__ Aout) {
  __shared__ __bf16 sK[128 * 64];  // 16 KB; P region after barrier 3
  __shared__ __bf16 sV[64 * 128];  // 16 KB

  const int tid = threadIdx.x;
  const int lane = tid & 63;
  const int wave = tid >> 6;
  const int quad = lane >> 4;
  const int l16 = lane & 15;

  const int bh = blockIdx.x >> 4;
  const int qt = 15 - (blockIdx.x & 15);  // longest first
  const int b = bh >> 4, h = bh & 15;
  const int qb = qt * 64;

  const size_t rowS = 3072;
  const __bf16* Qb = qkv + (size_t)b * 1024 * rowS + h * 64;
  const __bf16* Kb = Qb + 1024;
  const __bf16* VTb = VT + (size_t)bh * 64 * 1024;

  bf16x8 qA0, qA1;
  {
    const __bf16* qr = Qb + (size_t)(qb + wave * 16 + l16) * rowS + quad * 8;
    qA0 = *(const bf16x8*)qr;
    qA1 = *(const bf16x8*)(qr + 32);
  }

  f32x4 Oacc[4] = {};
  float m_run[4], l_run[4];
#pragma unroll
  for (int r = 0; r < 4; ++r) { m_run[r] = -3.0e38f; l_run[r] = 0.f; }

  __bf16* pw = sK + wave * 2048;  // per-wave P region: 16 q x 128 k
  const int swq = l16 & 7;
  const int kr = lane >> 3, ks = lane & 7;    // K staging: row-in-8, slot
  const int vd = lane >> 4, vs = lane & 15;   // V staging: d-in-4, slot

  for (int kb = 0; kb <= qb; kb += 128) {
    __syncthreads();  // prior iter's P/V reads done before restage

    // ---- stage K tile via global_load_lds: sK[key][slot s] = chunk s^(key&7)
#pragma unroll
    for (int i = 0; i < 4; ++i) {
      const int row = wave * 32 + i * 8 + kr;   // key in tile; row&7 == kr
      load_lds16(Kb + (size_t)(kb + row) * rowS + ((ks ^ kr) << 3),
                 &sK[(wave * 32 + i * 8) * 64]);
    }
    // ---- stage V^T tile: sV[d][slot s] = key-chunk s^(d&7)
#pragma unroll
    for (int i = 0; i < 4; ++i) {
      const int d = wave * 16 + i * 4 + vd;     // d&7 == (i*4+vd)&7
      const int gcv = vs ^ ((i * 4 + vd) & 7);
      load_lds16(VTb + (size_t)d * 1024 + kb + gcv * 8,
                 &sV[(wave * 16 + i * 4) * 128]);
    }
    __syncthreads();  // staged

    const bool maskNeeded = (kb + 128 > qb);

    // ---- QK^T: 8 key-subtiles, always computed (masked -> -10000)
    float sc[8][4];
#pragma unroll
    for (int n = 0; n < 8; ++n) {
      const int key = n * 16 + l16;
      bf16x8 kB0 = *(const bf16x8*)(&sK[key * 64 + ((quad ^ swq) << 3)]);
      bf16x8 kB1 = *(const bf16x8*)(&sK[key * 64 + (((quad + 4) ^ swq) << 3)]);
      f32x4 c = {};
      c = __builtin_amdgcn_mfma_f32_16x16x32_bf16(qA0, kB0, c, 0, 0, 0);
      c = __builtin_amdgcn_mfma_f32_16x16x32_bf16(qA1, kB1, c, 0, 0, 0);
#pragma unroll
      for (int r = 0; r < 4; ++r) sc[n][r] = c[r] * 0.125f;
    }
    if (maskNeeded) {
#pragma unroll
      for (int n = 0; n < 8; ++n) {
        const int kg = kb + n * 16 + l16;
#pragma unroll
        for (int r = 0; r < 4; ++r) {
          const int qg = qb + wave * 16 + quad * 4 + r;
          if (kg > qg) sc[n][r] = -10000.0f;
        }
      }
    }

    // ---- online softmax (row = quad group of 16 lanes)
    float alpha[4];
#pragma unroll
    for (int r = 0; r < 4; ++r) {
      float tmax = sc[0][r];
#pragma unroll
      for (int n = 1; n < 8; ++n) tmax = fmaxf(tmax, sc[n][r]);
      tmax = fmaxf(tmax, __shfl_xor(tmax, 1));
      tmax = fmaxf(tmax, __shfl_xor(tmax, 2));
      tmax = fmaxf(tmax, __shfl_xor(tmax, 4));
      tmax = fmaxf(tmax, __shfl_xor(tmax, 8));
      const float newm = fmaxf(m_run[r], tmax);
      alpha[r] = __expf(m_run[r] - newm);
      m_run[r] = newm;
      float ps = 0.f;
#pragma unroll
      for (int n = 0; n < 8; ++n) {
        float p = __expf(sc[n][r] - newm);
        sc[n][r] = p;
        ps += p;
      }
      ps += __shfl_xor(ps, 1);
      ps += __shfl_xor(ps, 2);
      ps += __shfl_xor(ps, 4);
      ps += __shfl_xor(ps, 8);
      l_run[r] = l_run[r] * alpha[r] + ps;
    }

    __syncthreads();  // all waves' sK reads done before P overwrites it

    // ---- P scatter: C-layout -> swizzled per-wave LDS (A-layout source)
    {
      const int kb8 = l16 >> 3, lo = l16 & 7;
#pragma unroll
      for (int n = 0; n < 8; ++n) {
        const int chunk = n * 2 + kb8;
#pragma unroll
        for (int r = 0; r < 4; ++r) {
          const int q = quad * 4 + r;
          pw[q * 128 + ((chunk ^ (q & 7)) << 3) + lo] = (__bf16)sc[n][r];
        }
      }
    }

    // ---- rescale O, then PV over 4 key-chunks
#pragma unroll
    for (int n = 0; n < 4; ++n)
#pragma unroll
      for (int r = 0; r < 4; ++r) Oacc[n][r] *= alpha[r];

#pragma unroll
    for (int c = 0; c < 4; ++c) {
      bf16x8 pA = *(const bf16x8*)(&pw[l16 * 128 + (((c * 4 + quad) ^ swq) << 3)]);
#pragma unroll
      for (int nt = 0; nt < 4; ++nt) {
        const int d = nt * 16 + l16;
        bf16x8 vB = *(const bf16x8*)(&sV[d * 128 + (((c * 4 + quad) ^ swq) << 3)]);
        Oacc[nt] = __builtin_amdgcn_mfma_f32_16x16x32_bf16(pA, vB, Oacc[nt], 0, 0, 0);
      }
    }
  }

  // ---- epilogue
  float inv[4];
#pragma unroll
  for (int r = 0; r < 4; ++r) inv[r] = 1.0f / l_run[r];
#pragma unroll
  for (int n = 0; n < 4; ++n) {
#pragma unroll
    for (int r = 0; r < 4; ++r) {
      const int q = qb + wave * 16 + quad * 4 + r;
      Aout[((size_t)b * 1024 + q) * 1024 + h * 64 + n * 16 + l16] =
          (__bf16)(Oacc[n][r] * inv[r]);
    }
  }
}

// ---------------- launch ----------------
extern "C" void kernel_launch(void* const* d_in, const int* in_sizes, int n_in,
                              void* d_out, int out_size, void* d_ws,
                              size_t ws_size, hipStream_t stream) {
  const float* x      = (const float*)d_in[0];
  const float* w_attn = (const float*)d_in[1];
  const float* b_attn = (const float*)d_in[2];
  const float* w_proj = (const float*)d_in[3];
  const float* b_proj = (const float*)d_in[4];
  float* out = (float*)d_out;

  char* ws = (char*)d_ws;
  __bf16* WT_attn = (__bf16*)(ws);                  //  6 MB
  __bf16* WT_proj = (__bf16*)(ws + 6291456);        //  2 MB
  __bf16* Xb      = (__bf16*)(ws + 8388608);        //  8 MB (reused as VT)
  __bf16* QKV     = (__bf16*)(ws + 16777216);       // 24 MB
  __bf16* Aattn   = (__bf16*)(ws + 41943040);       //  8 MB (total 48 MB)
  __bf16* VT      = Xb;  // x-as-bf16 dead after GEMM1; reuse for V^T

  transpose_f32_bf16<<<dim3(96, 32), dim3(32, 8), 0, stream>>>(
      w_attn, WT_attn, 1024, 3072);
  transpose_f32_bf16<<<dim3(32, 32), dim3(32, 8), 0, stream>>>(
      w_proj, WT_proj, 1024, 1024);
  f32_to_bf16<<<4096, 256, 0, stream>>>(x, Xb, 4096 * 1024);
  gemm_bt_bias<__bf16><<<dim3(24, 32), 256, 0, stream>>>(
      Xb, WT_attn, b_attn, QKV, 4096, 3072, 1024);
  transpose_v<<<1024, 256, 0, stream>>>(QKV, VT);
  attn_mfma<<<1024, 256, 0, stream>>>(QKV, VT, Aattn);
  gemm_bt_bias<float><<<dim3(8, 32), 256, 0, stream>>>(
      Aattn, WT_proj, b_proj, out, 4096, 1024, 1024);
}